// Round 7
// baseline (459.917 us; speedup 1.0000x reference)
//
#include <hip/hip_runtime.h>
#include <hip/hip_fp16.h>

typedef __attribute__((ext_vector_type(8))) _Float16 f16x8;
typedef __attribute__((ext_vector_type(2))) _Float16 f16x2;
typedef __attribute__((ext_vector_type(4))) float f32x4;
typedef __attribute__((ext_vector_type(16))) float f32x16;

#define ED 256
#define HID 128
#define NTILES 32768          // 1M points / 32 per tile
#define GRID 1024
#define K_REV 4.7746482927568605f   // 30 / (2*pi): sin(30x) = sin_rev(x*K_REV)

// d_ws layout (units: halfs)
#define WS_EMB0 0
#define WS_EMB1 131072
#define WS_W0   262144
#define WS_W1   294912
#define WS_W2   311296

__global__ void prep_kernel(const float* __restrict__ emb0, const float* __restrict__ emb1,
                            const float* __restrict__ w0, const float* __restrict__ w1,
                            const float* __restrict__ w2, f16x2* __restrict__ dst) {
  int idx = blockIdx.x * 256 + threadIdx.x;       // f32-pair index == f16-pair index
  const float* src; int rel;
  if      (idx <  65536) { src = emb0; rel = idx; }
  else if (idx < 131072) { src = emb1; rel = idx - 65536; }
  else if (idx < 147456) { src = w0;   rel = idx - 131072; }
  else if (idx < 155648) { src = w1;   rel = idx - 147456; }
  else if (idx < 155840) { src = w2;   rel = idx - 155648; }
  else return;
  float2 v = ((const float2*)src)[rel];
  f16x2 h; h[0] = (_Float16)v.x; h[1] = (_Float16)v.y;
  dst[idx] = h;
}

// sin(2*pi*t) via hw v_fract + v_sin
__device__ __forceinline__ float fast_sin_rev(float t) {
#if __has_builtin(__builtin_amdgcn_fractf) && __has_builtin(__builtin_amdgcn_sinf)
  return __builtin_amdgcn_sinf(__builtin_amdgcn_fractf(t));
#else
  return __sinf(6.28318530718f * (t - floorf(t)));
#endif
}

// (256,4): 4 blocks/CU min -> 16 waves/CU -> 128-VGPR cap. 4 independent
// barrier domains per CU for phase mixing (vs 2 in the 512-thr version).
__global__ __launch_bounds__(256, 4) void axisnet_kernel(
    const float* __restrict__ coords,
    const float* __restrict__ b0, const float* __restrict__ b1,
    const float* __restrict__ b2,
    const _Float16* __restrict__ ws, float* __restrict__ out)
{
  __shared__ _Float16 e_smem[32 * 256];    // 16 KiB, 512 B rows, XOR-swizzled
  __shared__ _Float16 h0_smem[32 * 128];   //  8 KiB, 256 B rows, XOR-swizzled
  __shared__ _Float16 h1_smem[32 * 128];   //  8 KiB
  char* eb  = (char*)e_smem;
  char* h0b = (char*)h0_smem;
  char* h1b = (char*)h1_smem;

  const _Float16* emb0h = ws + WS_EMB0;
  const _Float16* emb1h = ws + WS_EMB1;
  const _Float16* w0h   = ws + WS_W0;
  const _Float16* w1h   = ws + WS_W1;
  const _Float16* w2h   = ws + WS_W2;

  const int tid  = threadIdx.x;
  const int lane = tid & 63;
  const int wv   = tid >> 6;        // 0..3
  const int hi   = lane >> 5;       // 0/1  (32x32 k-half)
  const int l5   = lane & 31;
  const int g    = lane >> 4;       // 0..3 (16x16 k-group)
  const int lr   = lane & 15;

  // ---- persistent B fragments ----
  // L0 (32x32x16): wave wv owns cols 32*wv..+31. B: col=l5, k=16*ks+8*hi+j. 64 VGPR.
  f16x8 w0f[16];
  {
    const _Float16* p = w0h + (size_t)(32*wv + l5)*ED + 8*hi;
#pragma unroll
    for (int ks = 0; ks < 16; ++ks) w0f[ks] = *(const f16x8*)(p + 16*ks);
  }
  const float b0k = b0[32*wv + l5] * K_REV;

  // L1 (32x32x16): wave wv owns cols 32*wv..+31. 32 VGPR.
  f16x8 w1f[8];
  {
    const _Float16* p = w1h + (size_t)(32*wv + l5)*HID + 8*hi;
#pragma unroll
    for (int ks = 0; ks < 8; ++ks) w1f[ks] = *(const f16x8*)(p + 16*ks);
  }
  const float b1k = b1[32*wv + l5] * K_REV;
  const float b2v = (lr < 3) ? b2[lr] : 0.f;

  // ---- gather: 32-pt tile, wave handles 8 points; setup per lane, shfl-bcast ----
#define GATHER(T) do {                                                        \
    const int base2 = (T)*32 + 8*wv;                                          \
    float2 cp = ((const float2*)coords)[base2 + (lane & 7)];                  \
    float c0 = fminf(fmaxf(cp.x, -1.f), 0.999f);                              \
    float c1 = fminf(fmaxf(cp.y, -1.f), 0.999f);                              \
    float a0 = (0.5f*c0 + 0.5f) * 511.f;                                      \
    float a1 = (0.5f*c1 + 0.5f) * 511.f;                                      \
    int i0 = (int)a0, i1 = (int)a1;                                           \
    int o0 = i0 << 9, o1 = i1 << 9;      /* byte row offsets (512 B/row) */   \
    unsigned short ua = __builtin_bit_cast(unsigned short, (_Float16)(a0 - (float)i0)); \
    unsigned short ub = __builtin_bit_cast(unsigned short, (_Float16)(a1 - (float)i1)); \
    int wp = (int)ua | ((int)ub << 16);                                       \
    _Pragma("unroll")                                                         \
    for (int it = 0; it < 4; ++it) {                                          \
      int src = 2*it + hi;                                                    \
      int oo0 = __shfl(o0, src);                                              \
      int oo1 = __shfl(o1, src);                                              \
      int wpp = __shfl(wp, src);                                              \
      _Float16 wah = __builtin_bit_cast(_Float16, (unsigned short)(wpp & 0xffff));      \
      _Float16 wbh = __builtin_bit_cast(_Float16, (unsigned short)((unsigned)wpp >> 16)); \
      f16x8 wa8 = {wah,wah,wah,wah,wah,wah,wah,wah};                          \
      f16x8 wb8 = {wbh,wbh,wbh,wbh,wbh,wbh,wbh,wbh};                          \
      const char* px = (const char*)emb0h + oo0 + 16*l5;                      \
      const char* py = (const char*)emb1h + oo1 + 16*l5;                      \
      f16x8 x0 = *(const f16x8*)px, x1 = *(const f16x8*)(px + 512);           \
      f16x8 y0 = *(const f16x8*)py, y1 = *(const f16x8*)(py + 512);           \
      f16x8 ev = (x0 + wa8*(x1 - x0)) * (y0 + wb8*(y1 - y0));                 \
      int row = 8*wv + 2*it + hi;                                             \
      *(f16x8*)(eb + row*512 + ((16*l5) ^ ((row & 7) << 4))) = ev;            \
    } } while (0)

  GATHER(blockIdx.x);               // prologue: e(tile0)
  __syncthreads();                  // e ready

  // Per-tile schedule (2 barriers):
  //   [top] L2(prev) reads h1 (waves 0-1)  ||  L0(t) reads e, writes h0
  //   bar_B: h0 ready (everyone's h1/e reads done)
  //   GATHER(t+1) writes e  ||  L1 reads h0, writes h1
  //   bar_C: h1 + e(t+1) ready
  int prev_base = -1;
  for (int tile = blockIdx.x; tile < NTILES; tile += GRID) {
    const int base = tile * 32;

    // ---- L2(prev): [32x128]@[128x3], waves 0-1, reads h1; overlaps L0 ----
    if (prev_base >= 0 && wv < 2) {
      f32x4 acc2 = (f32x4)0.f;
#pragma unroll
      for (int ks = 0; ks < 4; ++ks) {
        f16x8 bfrag = (f16x8)0;
        if (lr < 3) bfrag = *(const f16x8*)(w2h + (size_t)lr*HID + 32*ks + 8*g);
        int row = 16*wv + lr;
        f16x8 a = *(const f16x8*)(h1b + row*256 + ((64*ks + 16*g) ^ ((row & 7) << 4)));
        acc2 = __builtin_amdgcn_mfma_f32_16x16x32_f16(a, bfrag, acc2, 0, 0, 0);
      }
      if (lr < 3) {
#pragma unroll
        for (int r = 0; r < 4; ++r) {
          int pt = prev_base + 16*wv + 4*g + r;
          out[pt*3 + lr] = acc2[r] + b2v;
        }
      }
    }

    // ---- L0: [32x256]@[256x128], wave = all 32 rows x its 32 cols, 32x32x16 ----
    {
      f32x16 acc0 = (f32x16)0.f;
      const char* abase = eb + l5*512;
      const int aswz = (l5 & 7) << 4;
      __builtin_amdgcn_s_setprio(1);
#pragma unroll
      for (int ks = 0; ks < 16; ++ks) {
        f16x8 a = *(const f16x8*)(abase + ((32*ks + 16*hi) ^ aswz));
        acc0 = __builtin_amdgcn_mfma_f32_32x32x16_f16(a, w0f[ks], acc0, 0, 0, 0);
      }
      __builtin_amdgcn_s_setprio(0);
      // C: col = 32*wv + l5, row = (reg&3)+8*(reg>>2)+4*hi
      const int colb = 2*(32*wv + l5);
#pragma unroll
      for (int reg = 0; reg < 16; ++reg) {
        float s = fast_sin_rev(fmaf(acc0[reg], K_REV, b0k));
        int hrow = (reg & 3) + 8*(reg >> 2) + 4*hi;
        *(_Float16*)(h0b + hrow*256 + (colb ^ ((hrow & 7) << 4))) = (_Float16)s;
      }
    }
    __syncthreads();                               // bar_B: h0 ready

    // ---- gather(t+GRID) (writes e) overlapped with L1 ----
    if (tile + GRID < NTILES) GATHER(tile + GRID);

    // ---- L1: [32x128]@[128x128], wave = 32 rows x its 32 cols, 32x32x16 ----
    {
      f32x16 acc1 = (f32x16)0.f;
      const char* abase = h0b + l5*256;
      const int aswz = (l5 & 7) << 4;
      __builtin_amdgcn_s_setprio(1);
#pragma unroll
      for (int ks = 0; ks < 8; ++ks) {
        f16x8 a = *(const f16x8*)(abase + ((32*ks + 16*hi) ^ aswz));
        acc1 = __builtin_amdgcn_mfma_f32_32x32x16_f16(a, w1f[ks], acc1, 0, 0, 0);
      }
      __builtin_amdgcn_s_setprio(0);
      const int colb = 2*(32*wv + l5);
#pragma unroll
      for (int reg = 0; reg < 16; ++reg) {
        float s = fast_sin_rev(fmaf(acc1[reg], K_REV, b1k));
        int hrow = (reg & 3) + 8*(reg >> 2) + 4*hi;
        *(_Float16*)(h1b + hrow*256 + (colb ^ ((hrow & 7) << 4))) = (_Float16)s;
      }
    }
    __syncthreads();                               // bar_C: h1 + e(t+1) ready
    prev_base = base;
  }

  // ---- epilogue: L2 of the last tile ----
  if (prev_base >= 0 && wv < 2) {
    f32x4 acc2 = (f32x4)0.f;
#pragma unroll
    for (int ks = 0; ks < 4; ++ks) {
      f16x8 bfrag = (f16x8)0;
      if (lr < 3) bfrag = *(const f16x8*)(w2h + (size_t)lr*HID + 32*ks + 8*g);
      int row = 16*wv + lr;
      f16x8 a = *(const f16x8*)(h1b + row*256 + ((64*ks + 16*g) ^ ((row & 7) << 4)));
      acc2 = __builtin_amdgcn_mfma_f32_16x16x32_f16(a, bfrag, acc2, 0, 0, 0);
    }
    if (lr < 3) {
#pragma unroll
      for (int r = 0; r < 4; ++r) {
        int pt = prev_base + 16*wv + 4*g + r;
        out[pt*3 + lr] = acc2[r] + b2v;
      }
    }
  }
}

extern "C" void kernel_launch(void* const* d_in, const int* in_sizes, int n_in,
                              void* d_out, int out_size, void* d_ws, size_t ws_size,
                              hipStream_t stream) {
  const float* coords = (const float*)d_in[0];
  const float* emb0   = (const float*)d_in[1];
  const float* emb1   = (const float*)d_in[2];
  const float* w0     = (const float*)d_in[3];
  const float* b0     = (const float*)d_in[4];
  const float* w1     = (const float*)d_in[5];
  const float* b1     = (const float*)d_in[6];
  const float* w2     = (const float*)d_in[7];
  const float* b2     = (const float*)d_in[8];
  float* out = (float*)d_out;
  _Float16* ws = (_Float16*)d_ws;

  prep_kernel<<<(155840 + 255)/256, 256, 0, stream>>>(emb0, emb1, w0, w1, w2, (f16x2*)ws);
  axisnet_kernel<<<GRID, 256, 0, stream>>>(coords, b0, b1, b2,
                                           (const _Float16*)ws, out);
}

// Round 8
// 295.372 us; speedup vs baseline: 1.5571x; 1.5571x over previous
//
#include <hip/hip_runtime.h>
#include <hip/hip_fp16.h>

typedef __attribute__((ext_vector_type(8))) _Float16 f16x8;
typedef __attribute__((ext_vector_type(2))) _Float16 f16x2;
typedef __attribute__((ext_vector_type(4))) float f32x4;
typedef __attribute__((ext_vector_type(16))) float f32x16;

#define ED 256
#define HID 128
#define NTILES 32768          // 1M points / 32 per tile
#define GRID 1024
#define K_REV 4.7746482927568605f   // 30 / (2*pi): sin(30x) = sin_rev(x*K_REV)

// d_ws layout (units: halfs)
#define WS_EMB0 0
#define WS_EMB1 131072
#define WS_W0   262144
#define WS_W1   294912
#define WS_W2   311296

__global__ void prep_kernel(const float* __restrict__ emb0, const float* __restrict__ emb1,
                            const float* __restrict__ w0, const float* __restrict__ w1,
                            const float* __restrict__ w2, f16x2* __restrict__ dst) {
  int idx = blockIdx.x * 256 + threadIdx.x;       // f32-pair index == f16-pair index
  const float* src; int rel;
  if      (idx <  65536) { src = emb0; rel = idx; }
  else if (idx < 131072) { src = emb1; rel = idx - 65536; }
  else if (idx < 147456) { src = w0;   rel = idx - 131072; }
  else if (idx < 155648) { src = w1;   rel = idx - 147456; }
  else if (idx < 155840) { src = w2;   rel = idx - 155648; }
  else return;
  float2 v = ((const float2*)src)[rel];
  f16x2 h; h[0] = (_Float16)v.x; h[1] = (_Float16)v.y;
  dst[idx] = h;
}

// sin(2*pi*t) via hw v_fract + v_sin
__device__ __forceinline__ float fast_sin_rev(float t) {
#if __has_builtin(__builtin_amdgcn_fractf) && __has_builtin(__builtin_amdgcn_sinf)
  return __builtin_amdgcn_sinf(__builtin_amdgcn_fractf(t));
#else
  return __sinf(6.28318530718f * (t - floorf(t)));
#endif
}

// Empirical gfx950/hipcc rule (rounds 3-7): VGPR cap = 256 / arg2.
// (256,2) -> 128-reg cap; HW occupancy then 4 waves/SIMD = 4 blocks/CU
// = 4 independent barrier domains for phase mixing.
__global__ __launch_bounds__(256, 2) void axisnet_kernel(
    const float* __restrict__ coords,
    const float* __restrict__ b0, const float* __restrict__ b1,
    const float* __restrict__ b2,
    const _Float16* __restrict__ ws, float* __restrict__ out)
{
  __shared__ _Float16 e_smem[32 * 256];    // 16 KiB, 512 B rows, XOR-swizzled
  __shared__ _Float16 h0_smem[32 * 128];   //  8 KiB, 256 B rows, XOR-swizzled
  __shared__ _Float16 h1_smem[32 * 128];   //  8 KiB
  char* eb  = (char*)e_smem;
  char* h0b = (char*)h0_smem;
  char* h1b = (char*)h1_smem;

  const _Float16* emb0h = ws + WS_EMB0;
  const _Float16* emb1h = ws + WS_EMB1;
  const _Float16* w0h   = ws + WS_W0;
  const _Float16* w1h   = ws + WS_W1;
  const _Float16* w2h   = ws + WS_W2;

  const int tid  = threadIdx.x;
  const int lane = tid & 63;
  const int wv   = tid >> 6;        // 0..3
  const int hi   = lane >> 5;       // 0/1  (32x32 k-half)
  const int l5   = lane & 31;
  const int g    = lane >> 4;       // 0..3 (16x16 k-group)
  const int lr   = lane & 15;

  // ---- persistent B fragments ----
  // L0 (32x32x16): wave wv owns cols 32*wv..+31. B: col=l5, k=16*ks+8*hi+j. 64 VGPR.
  f16x8 w0f[16];
  {
    const _Float16* p = w0h + (size_t)(32*wv + l5)*ED + 8*hi;
#pragma unroll
    for (int ks = 0; ks < 16; ++ks) w0f[ks] = *(const f16x8*)(p + 16*ks);
  }
  const float b0k = b0[32*wv + l5] * K_REV;

  // L1 (32x32x16): wave wv owns cols 32*wv..+31. 32 VGPR.
  f16x8 w1f[8];
  {
    const _Float16* p = w1h + (size_t)(32*wv + l5)*HID + 8*hi;
#pragma unroll
    for (int ks = 0; ks < 8; ++ks) w1f[ks] = *(const f16x8*)(p + 16*ks);
  }
  const float b1k = b1[32*wv + l5] * K_REV;
  const float b2v = (lr < 3) ? b2[lr] : 0.f;

  // ---- gather: 32-pt tile, wave handles 8 points; setup per lane, shfl-bcast ----
#define GATHER(T) do {                                                        \
    const int base2 = (T)*32 + 8*wv;                                          \
    float2 cp = ((const float2*)coords)[base2 + (lane & 7)];                  \
    float c0 = fminf(fmaxf(cp.x, -1.f), 0.999f);                              \
    float c1 = fminf(fmaxf(cp.y, -1.f), 0.999f);                              \
    float a0 = (0.5f*c0 + 0.5f) * 511.f;                                      \
    float a1 = (0.5f*c1 + 0.5f) * 511.f;                                      \
    int i0 = (int)a0, i1 = (int)a1;                                           \
    int o0 = i0 << 9, o1 = i1 << 9;      /* byte row offsets (512 B/row) */   \
    unsigned short ua = __builtin_bit_cast(unsigned short, (_Float16)(a0 - (float)i0)); \
    unsigned short ub = __builtin_bit_cast(unsigned short, (_Float16)(a1 - (float)i1)); \
    int wp = (int)ua | ((int)ub << 16);                                       \
    _Pragma("unroll")                                                         \
    for (int it = 0; it < 4; ++it) {                                          \
      int src = 2*it + hi;                                                    \
      int oo0 = __shfl(o0, src);                                              \
      int oo1 = __shfl(o1, src);                                              \
      int wpp = __shfl(wp, src);                                              \
      _Float16 wah = __builtin_bit_cast(_Float16, (unsigned short)(wpp & 0xffff));      \
      _Float16 wbh = __builtin_bit_cast(_Float16, (unsigned short)((unsigned)wpp >> 16)); \
      f16x8 wa8 = {wah,wah,wah,wah,wah,wah,wah,wah};                          \
      f16x8 wb8 = {wbh,wbh,wbh,wbh,wbh,wbh,wbh,wbh};                          \
      const char* px = (const char*)emb0h + oo0 + 16*l5;                      \
      const char* py = (const char*)emb1h + oo1 + 16*l5;                      \
      f16x8 x0 = *(const f16x8*)px, x1 = *(const f16x8*)(px + 512);           \
      f16x8 y0 = *(const f16x8*)py, y1 = *(const f16x8*)(py + 512);           \
      f16x8 ev = (x0 + wa8*(x1 - x0)) * (y0 + wb8*(y1 - y0));                 \
      int row = 8*wv + 2*it + hi;                                             \
      *(f16x8*)(eb + row*512 + ((16*l5) ^ ((row & 7) << 4))) = ev;            \
    } } while (0)

  GATHER(blockIdx.x);               // prologue: e(tile0)
  __syncthreads();                  // e ready

  // Per-tile schedule (2 barriers):
  //   [top] L2(prev) reads h1 (waves 0-1)  ||  L0(t) reads e, writes h0
  //   bar_B: h0 ready (everyone's h1/e reads done)
  //   GATHER(t+1) writes e  ||  L1 reads h0, writes h1
  //   bar_C: h1 + e(t+1) ready
  int prev_base = -1;
  for (int tile = blockIdx.x; tile < NTILES; tile += GRID) {
    const int base = tile * 32;

    // ---- L2(prev): [32x128]@[128x3], waves 0-1, reads h1; overlaps L0 ----
    if (prev_base >= 0 && wv < 2) {
      f32x4 acc2 = (f32x4)0.f;
#pragma unroll
      for (int ks = 0; ks < 4; ++ks) {
        f16x8 bfrag = (f16x8)0;
        if (lr < 3) bfrag = *(const f16x8*)(w2h + (size_t)lr*HID + 32*ks + 8*g);
        int row = 16*wv + lr;
        f16x8 a = *(const f16x8*)(h1b + row*256 + ((64*ks + 16*g) ^ ((row & 7) << 4)));
        acc2 = __builtin_amdgcn_mfma_f32_16x16x32_f16(a, bfrag, acc2, 0, 0, 0);
      }
      if (lr < 3) {
#pragma unroll
        for (int r = 0; r < 4; ++r) {
          int pt = prev_base + 16*wv + 4*g + r;
          out[pt*3 + lr] = acc2[r] + b2v;
        }
      }
    }

    // ---- L0: [32x256]@[256x128], wave = all 32 rows x its 32 cols, 32x32x16 ----
    {
      f32x16 acc0 = (f32x16)0.f;
      const char* abase = eb + l5*512;
      const int aswz = (l5 & 7) << 4;
      __builtin_amdgcn_s_setprio(1);
#pragma unroll
      for (int ks = 0; ks < 16; ++ks) {
        f16x8 a = *(const f16x8*)(abase + ((32*ks + 16*hi) ^ aswz));
        acc0 = __builtin_amdgcn_mfma_f32_32x32x16_f16(a, w0f[ks], acc0, 0, 0, 0);
      }
      __builtin_amdgcn_s_setprio(0);
      // C: col = 32*wv + l5, row = (reg&3)+8*(reg>>2)+4*hi
      const int colb = 2*(32*wv + l5);
#pragma unroll
      for (int reg = 0; reg < 16; ++reg) {
        float s = fast_sin_rev(fmaf(acc0[reg], K_REV, b0k));
        int hrow = (reg & 3) + 8*(reg >> 2) + 4*hi;
        *(_Float16*)(h0b + hrow*256 + (colb ^ ((hrow & 7) << 4))) = (_Float16)s;
      }
    }
    __syncthreads();                               // bar_B: h0 ready

    // ---- gather(t+GRID) (writes e) overlapped with L1 ----
    if (tile + GRID < NTILES) GATHER(tile + GRID);

    // ---- L1: [32x128]@[128x128], wave = 32 rows x its 32 cols, 32x32x16 ----
    {
      f32x16 acc1 = (f32x16)0.f;
      const char* abase = h0b + l5*256;
      const int aswz = (l5 & 7) << 4;
      __builtin_amdgcn_s_setprio(1);
#pragma unroll
      for (int ks = 0; ks < 8; ++ks) {
        f16x8 a = *(const f16x8*)(abase + ((32*ks + 16*hi) ^ aswz));
        acc1 = __builtin_amdgcn_mfma_f32_32x32x16_f16(a, w1f[ks], acc1, 0, 0, 0);
      }
      __builtin_amdgcn_s_setprio(0);
      const int colb = 2*(32*wv + l5);
#pragma unroll
      for (int reg = 0; reg < 16; ++reg) {
        float s = fast_sin_rev(fmaf(acc1[reg], K_REV, b1k));
        int hrow = (reg & 3) + 8*(reg >> 2) + 4*hi;
        *(_Float16*)(h1b + hrow*256 + (colb ^ ((hrow & 7) << 4))) = (_Float16)s;
      }
    }
    __syncthreads();                               // bar_C: h1 + e(t+1) ready
    prev_base = base;
  }

  // ---- epilogue: L2 of the last tile ----
  if (prev_base >= 0 && wv < 2) {
    f32x4 acc2 = (f32x4)0.f;
#pragma unroll
    for (int ks = 0; ks < 4; ++ks) {
      f16x8 bfrag = (f16x8)0;
      if (lr < 3) bfrag = *(const f16x8*)(w2h + (size_t)lr*HID + 32*ks + 8*g);
      int row = 16*wv + lr;
      f16x8 a = *(const f16x8*)(h1b + row*256 + ((64*ks + 16*g) ^ ((row & 7) << 4)));
      acc2 = __builtin_amdgcn_mfma_f32_16x16x32_f16(a, bfrag, acc2, 0, 0, 0);
    }
    if (lr < 3) {
#pragma unroll
      for (int r = 0; r < 4; ++r) {
        int pt = prev_base + 16*wv + 4*g + r;
        out[pt*3 + lr] = acc2[r] + b2v;
      }
    }
  }
}

extern "C" void kernel_launch(void* const* d_in, const int* in_sizes, int n_in,
                              void* d_out, int out_size, void* d_ws, size_t ws_size,
                              hipStream_t stream) {
  const float* coords = (const float*)d_in[0];
  const float* emb0   = (const float*)d_in[1];
  const float* emb1   = (const float*)d_in[2];
  const float* w0     = (const float*)d_in[3];
  const float* b0     = (const float*)d_in[4];
  const float* w1     = (const float*)d_in[5];
  const float* b1     = (const float*)d_in[6];
  const float* w2     = (const float*)d_in[7];
  const float* b2     = (const float*)d_in[8];
  float* out = (float*)d_out;
  _Float16* ws = (_Float16*)d_ws;

  prep_kernel<<<(155840 + 255)/256, 256, 0, stream>>>(emb0, emb1, w0, w1, w2, (f16x2*)ws);
  axisnet_kernel<<<GRID, 256, 0, stream>>>(coords, b0, b1, b2,
                                           (const _Float16*)ws, out);
}